// Round 8
// baseline (102.189 us; speedup 1.0000x reference)
//
#include <hip/hip_runtime.h>

#define BB 16
#define NN 300
#define PP 100
#define LL 32
#define HH 768
#define WW 768
#define NDETBLK 19              // ceil(4800/256)
#define ROWBLK 192              // row-blocks per batch in k_scan (4 rows each)

__device__ __forceinline__ float relu_f(float x) { return fmaxf(x, 0.f); }

// ---------------------------------------------------------------------------
// K_A: row-prefix P[b][y][x] = prefix_x(seg[b,2,y]-seg[b,1,y]).
// One WAVE per row: lane owns 12 contiguous floats -> 11 reg adds + one
// 6-step wave scan; coalesced float4 read/write, no LDS, no carries.
// Blocks 0..18 additionally emit per-box metadata (softmax conf + pixel box).
// Grid: BB*ROWBLK = 3072 blocks x 256 thr. Tiny LDS -> high occupancy.
// ---------------------------------------------------------------------------
__global__ __launch_bounds__(256) void k_scan(const float* __restrict__ seg,
                                              const float* __restrict__ det_boxes,
                                              const float* __restrict__ logits,
                                              float* __restrict__ P,
                                              int* __restrict__ metaX,
                                              int* __restrict__ metaY,
                                              float* __restrict__ confV) {
    const int blk  = blockIdx.x;
    const int b    = blk / ROWBLK;
    const int t    = threadIdx.x;
    const int wave = t >> 6, lane = t & 63;
    const int y    = (blk % ROWBLK) * 4 + wave;

    const float* p1 = seg + ((size_t)(b * 3 + 1) * HH + y) * WW + 12 * lane;
    const float* p2 = seg + ((size_t)(b * 3 + 2) * HH + y) * WW + 12 * lane;
    float4 A0 = *(const float4*)(p1);
    float4 A1 = *(const float4*)(p1 + 4);
    float4 A2 = *(const float4*)(p1 + 8);
    float4 B0 = *(const float4*)(p2);
    float4 B1 = *(const float4*)(p2 + 4);
    float4 B2 = *(const float4*)(p2 + 8);
    float r0  = B0.x - A0.x;
    float r1  = r0 + (B0.y - A0.y);
    float r2  = r1 + (B0.z - A0.z);
    float r3  = r2 + (B0.w - A0.w);
    float r4  = r3 + (B1.x - A1.x);
    float r5  = r4 + (B1.y - A1.y);
    float r6  = r5 + (B1.z - A1.z);
    float r7  = r6 + (B1.w - A1.w);
    float r8  = r7 + (B2.x - A2.x);
    float r9  = r8 + (B2.y - A2.y);
    float r10 = r9 + (B2.z - A2.z);
    float r11 = r10 + (B2.w - A2.w);
    float total = r11;
    float incl = total;
    #pragma unroll
    for (int d = 1; d < 64; d <<= 1) {
        float u = __shfl_up(incl, d, 64);
        if (lane >= d) incl += u;
    }
    float excl = incl - total;
    float* Pq = P + ((size_t)b * HH + y) * WW + 12 * lane;
    float4 w0 = { r0 + excl, r1 + excl, r2  + excl, r3  + excl };
    float4 w1 = { r4 + excl, r5 + excl, r6  + excl, r7  + excl };
    float4 w2 = { r8 + excl, r9 + excl, r10 + excl, r11 + excl };
    *(float4*)(Pq)     = w0;
    *(float4*)(Pq + 4) = w1;
    *(float4*)(Pq + 8) = w2;

    // ---- meta duty on first 19 blocks -------------------------------------
    if (blk < NDETBLK) {
        const int idx = blk * 256 + t;
        if (idx < BB * NN) {
            const float* lg = logits + (size_t)idx * 7;
            float m = lg[0];
            #pragma unroll
            for (int i = 1; i < 7; ++i) m = fmaxf(m, lg[i]);
            float sum = 0.f;
            #pragma unroll
            for (int i = 0; i < 7; ++i) sum += expf(lg[i] - m);
            float conf = 1.f / sum;
            confV[idx] = conf;

            const float* bxp = det_boxes + (size_t)idx * 4;
            float cx = bxp[0], cy = bxp[1], w = bxp[2], h = bxp[3];
            int x1 = (int)floorf((cx - w * 0.5f) * (float)WW);
            int y1 = (int)floorf((cy - h * 0.5f) * (float)HH);
            int x2 = (int)floorf((cx + w * 0.5f) * (float)WW);
            int y2 = (int)floorf((cy + h * 0.5f) * (float)HH);
            x1 = min(max(x1, 0), WW - 1); y1 = min(max(y1, 0), HH - 1);
            x2 = min(max(x2, 0), WW - 1); y2 = min(max(y2, 0), HH - 1);
            bool valid = (conf >= 0.3f) && (x2 > x1) && (y2 > y1);
            metaX[idx] = valid ? (x1 | ((x2 - 1) << 16)) : 0;
            metaY[idx] = valid ? (y1 | (y2 << 16)) : 0;
        }
    }
}

// ---------------------------------------------------------------------------
// K_B: one WAVE per box; lanes stride rows reading P[y][x2-1] (- P[y][x1-1]).
// Scattered 4B reads served by L3 (P = 37.7MB, fully resident). Shuffle
// reduce -> per-block partial (fixed order, deterministic).
// Grid: 1200 blocks x 256 thr.
// ---------------------------------------------------------------------------
__global__ __launch_bounds__(256) void k_boxsum(const float* __restrict__ P,
                                                const int* __restrict__ metaX,
                                                const int* __restrict__ metaY,
                                                const float* __restrict__ confV,
                                                float* __restrict__ detPart) {
    const int t = threadIdx.x;
    const int wave = t >> 6, lane = t & 63;
    const int box = blockIdx.x * 4 + wave;      // < 4800
    const int b = box / NN;

    int mx = metaX[box], my = metaY[box];
    float contrib = 0.f;
    if (my != 0) {
        int x1 = mx & 0xffff, x2m1 = mx >> 16;
        int y1 = my & 0xffff, y2 = my >> 16;
        const float* base = P + (size_t)b * HH * WW;
        float acc = 0.f;
        if (x1 > 0) {
            for (int y = y1 + lane; y < y2; y += 64) {
                const float* row = base + (size_t)y * WW;
                acc += row[x2m1] - row[x1 - 1];
            }
        } else {
            for (int y = y1 + lane; y < y2; y += 64) {
                acc += base[(size_t)y * WW + x2m1];
            }
        }
        #pragma unroll
        for (int d = 32; d > 0; d >>= 1) acc += __shfl_down(acc, d, 64);
        if (lane == 0) {
            float area = (float)((y2 - y1) * (x2m1 + 1 - x1));
            contrib = relu_f(acc / area) * confV[box];
        }
    }

    __shared__ float red[4];
    if (lane == 0) red[wave] = contrib;
    __syncthreads();
    if (t == 0) detPart[blockIdx.x] = red[0] + red[1] + red[2] + red[3];
}

// ---------------------------------------------------------------------------
// K_C: plate IoU + OCR per batch. 16 blocks x 128 threads. Uses confV.
// ---------------------------------------------------------------------------
__global__ __launch_bounds__(128) void k_plate_ocr(const float* __restrict__ det_boxes,
                                                   const float* __restrict__ confV,
                                                   const float* __restrict__ plate_boxes,
                                                   const float* __restrict__ plate_conf,
                                                   const float* __restrict__ ocr,
                                                   float* __restrict__ platePart,
                                                   float* __restrict__ plateCnt,
                                                   float* __restrict__ ocrPart) {
    const float CONF_TH = 0.3f, MIN_IOU = 0.5f, OCR_TH = 0.7f;
    int b = blockIdx.x;
    int t = threadIdx.x;

    __shared__ float vx1[NN], vy1[NN], vx2[NN], vy2[NN], va[NN], vcf[NN];
    __shared__ int anyv;
    __shared__ float redf[128];
    __shared__ int   redi[128];

    if (t == 0) anyv = 0;
    __syncthreads();

    for (int j = t; j < NN; j += 128) {
        const float* bxp = det_boxes + ((size_t)b * NN + j) * 4;
        float cx = bxp[0], cy = bxp[1], w = bxp[2], h = bxp[3];
        float x1 = cx - w * 0.5f, y1 = cy - h * 0.5f;
        float x2 = cx + w * 0.5f, y2 = cy + h * 0.5f;
        vx1[j] = x1; vy1[j] = y1; vx2[j] = x2; vy2[j] = y2;
        va[j] = (x2 - x1) * (y2 - y1);
        float cc = confV[b * NN + j];
        vcf[j] = cc;
        if (cc > CONF_TH) atomicOr(&anyv, 1);
    }
    __syncthreads();

    float term = 0.f; int pv = 0; float pcf = -1e30f;
    if (t < PP) {
        const float* bxp = plate_boxes + ((size_t)b * PP + t) * 4;
        float cx = bxp[0], cy = bxp[1], w = bxp[2], h = bxp[3];
        float px1 = cx - w * 0.5f, py1 = cy - h * 0.5f;
        float px2 = cx + w * 0.5f, py2 = cy + h * 0.5f;
        float a1 = (px2 - px1) * (py2 - py1);
        pcf = plate_conf[b * PP + t];
        pv = (pcf > CONF_TH) ? 1 : 0;
        float max_iou = -1.f;
        for (int j = 0; j < NN; ++j) {
            if (vcf[j] > CONF_TH) {
                float ltx = fmaxf(px1, vx1[j]);
                float lty = fmaxf(py1, vy1[j]);
                float rbx = fminf(px2, vx2[j]);
                float rby = fminf(py2, vy2[j]);
                float iw = fmaxf(rbx - ltx, 0.f);
                float ih = fmaxf(rby - lty, 0.f);
                float inter = iw * ih;
                float uni = a1 + va[j] - inter;
                float iou = inter / (uni + 1e-8f);
                max_iou = fmaxf(max_iou, iou);
            }
        }
        if (pv) term = relu_f(MIN_IOU - max_iou) * pcf;
    }

    redf[t] = term; redi[t] = pv;
    __syncthreads();
    for (int s = 64; s > 0; s >>= 1) {
        if (t < s) { redf[t] += redf[t + s]; redi[t] += redi[t + s]; }
        __syncthreads();
    }
    float termsum = redf[0];
    int   cnt     = redi[0];
    __syncthreads();

    float osum = 0.f;
    if (t < LL) {
        const float* op = ocr + ((size_t)b * LL + t) * 37;
        float m = op[0];
        #pragma unroll
        for (int i = 1; i < 37; ++i) m = fmaxf(m, op[i]);
        osum = m;
    }
    redf[t] = osum;
    __syncthreads();
    for (int s = 64; s > 0; s >>= 1) {
        if (t < s) redf[t] += redf[t + s];
        __syncthreads();
    }
    float avg_ocr = redf[0] / (float)LL;
    __syncthreads();

    redf[t] = (t < PP) ? pcf : -1e30f;
    __syncthreads();
    for (int s = 64; s > 0; s >>= 1) {
        if (t < s) redf[t] = fmaxf(redf[t], redf[t + s]);
        __syncthreads();
    }
    float max_plate = redf[0];

    if (t == 0) {
        platePart[b] = (cnt > 0 && anyv) ? termsum : 0.f;
        plateCnt[b]  = (float)cnt;
        ocrPart[b]   = (avg_ocr > OCR_TH) ? relu_f(avg_ocr - max_plate) : 0.f;
    }
}

// ---------------------------------------------------------------------------
// K_D: final deterministic combine (fixed-order f64 tree over 1200 partials).
// ---------------------------------------------------------------------------
__global__ __launch_bounds__(256) void k_final(const float* __restrict__ detPart,
                                               const float* __restrict__ platePart,
                                               const float* __restrict__ plateCnt,
                                               const float* __restrict__ ocrPart,
                                               float* __restrict__ out) {
    __shared__ double red[256];
    int t = threadIdx.x;
    double s = 0.0;
    for (int i = t; i < 1200; i += 256) s += (double)detPart[i];
    red[t] = s;
    __syncthreads();
    for (int k = 128; k > 0; k >>= 1) {
        if (t < k) red[t] += red[t + k];
        __syncthreads();
    }
    if (t == 0) {
        double ps = 0.0, pc = 0.0, os = 0.0;
        for (int b = 0; b < BB; ++b) {
            ps += (double)platePart[b];
            pc += (double)plateCnt[b];
            os += (double)ocrPart[b];
        }
        float det_seg   = (float)red[0] / (float)(BB * NN);
        float plate_det = (float)ps / fmaxf((float)pc, 1.f);
        float ocr_plate = (float)os / (float)BB;
        out[0] = 0.1f * det_seg + 0.1f * plate_det + 0.1f * ocr_plate;
    }
}

extern "C" void kernel_launch(void* const* d_in, const int* in_sizes, int n_in,
                              void* d_out, int out_size, void* d_ws, size_t ws_size,
                              hipStream_t stream) {
    const float* det_boxes   = (const float*)d_in[0];
    const float* det_logits  = (const float*)d_in[1];
    const float* seg_masks   = (const float*)d_in[2];
    const float* plate_boxes = (const float*)d_in[3];
    const float* plate_conf  = (const float*)d_in[4];
    const float* ocr_probs   = (const float*)d_in[5];
    float* out = (float*)d_out;

    // workspace layout
    float* P          = (float*)d_ws;                     // BB*HH*WW = 37.7 MB
    float* confV      = P + (size_t)BB * HH * WW;         // 4800
    float* detPart    = confV + BB * NN;                  // 1200
    float* platePart  = detPart + 1200;                   // 16
    float* plateCnt   = platePart + BB;                   // 16
    float* ocrPart    = plateCnt + BB;                    // 16
    int*   metaX      = (int*)(ocrPart + BB);             // 4800
    int*   metaY      = metaX + BB * NN;                  // 4800

    k_scan<<<BB * ROWBLK, 256, 0, stream>>>(seg_masks, det_boxes, det_logits,
                                            P, metaX, metaY, confV);
    k_boxsum<<<1200, 256, 0, stream>>>(P, metaX, metaY, confV, detPart);
    k_plate_ocr<<<BB, 128, 0, stream>>>(det_boxes, confV, plate_boxes,
                                        plate_conf, ocr_probs,
                                        platePart, plateCnt, ocrPart);
    k_final<<<1, 256, 0, stream>>>(detPart, platePart, plateCnt, ocrPart, out);
}

// Round 9
// 74.606 us; speedup vs baseline: 1.3697x; 1.3697x over previous
//
#include <hip/hip_runtime.h>

#define BB 16
#define NN 300
#define PP 100
#define LL 32
#define HH 768
#define WW 768
#define BAND 8                  // rows per band-block
#define NBAND (HH / BAND)       // 96
#define PSTR 772                // LDS row stride in floats (16B-aligned)
#define NDETBLK 19              // ceil(4800/256)

__device__ __forceinline__ float relu_f(float x) { return fmaxf(x, 0.f); }

// ---------------------------------------------------------------------------
// K0: per-box metadata (softmax conf + pixel coords), once.
// ---------------------------------------------------------------------------
__global__ __launch_bounds__(256) void k_meta(const float* __restrict__ det_boxes,
                                              const float* __restrict__ logits,
                                              int* __restrict__ metaX,
                                              int* __restrict__ metaY,
                                              float* __restrict__ confV) {
    const int idx = blockIdx.x * 256 + threadIdx.x;
    if (idx >= BB * NN) return;
    const float* lg = logits + (size_t)idx * 7;
    float m = lg[0];
    #pragma unroll
    for (int i = 1; i < 7; ++i) m = fmaxf(m, lg[i]);
    float sum = 0.f;
    #pragma unroll
    for (int i = 0; i < 7; ++i) sum += expf(lg[i] - m);
    float conf = 1.f / sum;
    confV[idx] = conf;

    const float* bxp = det_boxes + (size_t)idx * 4;
    float cx = bxp[0], cy = bxp[1], w = bxp[2], h = bxp[3];
    int x1 = (int)floorf((cx - w * 0.5f) * (float)WW);
    int y1 = (int)floorf((cy - h * 0.5f) * (float)HH);
    int x2 = (int)floorf((cx + w * 0.5f) * (float)WW);
    int y2 = (int)floorf((cy + h * 0.5f) * (float)HH);
    x1 = min(max(x1, 0), WW - 1); y1 = min(max(y1, 0), HH - 1);
    x2 = min(max(x2, 0), WW - 1); y2 = min(max(y2, 0), HH - 1);
    bool valid = (conf >= 0.3f) && (x2 > x1) && (y2 > y1);
    metaX[idx] = valid ? (x1 | ((x2 - 1) << 16)) : 0;
    metaY[idx] = valid ? (y1 | (y2 << 16)) : 0;
}

// ---------------------------------------------------------------------------
// K1: one block per (batch, 8-row band). UNIT-LANE-STRIDE loads only:
// row = 3 chunks of 256 floats; lane reads float4 at c*256 + 4*lane
// (64 lanes x 16B = contiguous 1KB per instruction). All 12 loads issued
// before scan math. 3-chunk shuffle scan with scalar carry. Phase B:
// thread-per-box over LDS rows; coalesced partial write.
// Grid: 1536 blocks x 256 thr; LDS 24.7 KB.
// ---------------------------------------------------------------------------
__global__ __launch_bounds__(256) void k_band(const float* __restrict__ seg,
                                              const int* __restrict__ metaX,
                                              const int* __restrict__ metaY,
                                              float* __restrict__ detPartial) {
    const int blk  = blockIdx.x;
    const int b    = blk / NBAND;
    const int band = blk % NBAND;
    const int y0   = band * BAND;
    const int t    = threadIdx.x;
    const int wave = t >> 6, lane = t & 63;

    __shared__ float P[BAND * PSTR];   // 24704 B

    const float* c1 = seg + (size_t)(b * 3 + 1) * HH * WW;
    const float* c2 = seg + (size_t)(b * 3 + 2) * HH * WW;

    // ---- Phase A: wave handles rows wave*2, wave*2+1 ----------------------
    // prefetch all 12 float4 (unit lane stride), then scan
    float4 a0, a1, a2, a3, a4, a5;     // ch1: row0 c0..2, row1 c0..2
    float4 v0, v1, v2, v3, v4, v5;     // ch2
    {
        const int yA = y0 + wave * 2;
        const int yB = yA + 1;
        const float4* q1A = (const float4*)(c1 + (size_t)yA * WW);
        const float4* q2A = (const float4*)(c2 + (size_t)yA * WW);
        const float4* q1B = (const float4*)(c1 + (size_t)yB * WW);
        const float4* q2B = (const float4*)(c2 + (size_t)yB * WW);
        a0 = q1A[lane];       a1 = q1A[64 + lane];  a2 = q1A[128 + lane];
        a3 = q1B[lane];       a4 = q1B[64 + lane];  a5 = q1B[128 + lane];
        v0 = q2A[lane];       v1 = q2A[64 + lane];  v2 = q2A[128 + lane];
        v3 = q2B[lane];       v4 = q2B[64 + lane];  v5 = q2B[128 + lane];
    }
    #pragma unroll
    for (int rr = 0; rr < 2; ++rr) {
        const int r = wave * 2 + rr;
        float* Prow = P + r * PSTR;
        float carry = 0.f;
        #pragma unroll
        for (int c = 0; c < 3; ++c) {
            float4 A = (rr == 0) ? (c == 0 ? a0 : c == 1 ? a1 : a2)
                                 : (c == 0 ? a3 : c == 1 ? a4 : a5);
            float4 V = (rr == 0) ? (c == 0 ? v0 : c == 1 ? v1 : v2)
                                 : (c == 0 ? v3 : c == 1 ? v4 : v5);
            float s0 = V.x - A.x;
            float s1 = s0 + (V.y - A.y);
            float s2 = s1 + (V.z - A.z);
            float s3 = s2 + (V.w - A.w);
            float tot = s3, incl = tot;
            #pragma unroll
            for (int d = 1; d < 64; d <<= 1) {
                float u = __shfl_up(incl, d, 64);
                if (lane >= d) incl += u;
            }
            float base = carry + incl - tot;
            float4 w = { s0 + base, s1 + base, s2 + base, s3 + base };
            *(float4*)(Prow + c * 256 + 4 * lane) = w;
            carry += __shfl(incl, 63, 64);
        }
    }
    __syncthreads();

    // ---- Phase B: per-box band partials, coalesced write ------------------
    const int* mXb = metaX + (size_t)b * NN;
    const int* mYb = metaY + (size_t)b * NN;
    float* outp = detPartial + ((size_t)b * NBAND + band) * NN;
    for (int j = t; j < NN; j += 256) {
        int mx = mXb[j], my = mYb[j];
        int y1 = my & 0xffff, y2 = my >> 16;
        int lo = max(y1, y0), hi = min(y2, y0 + BAND);
        float acc = 0.f;
        if (lo < hi) {
            int x1 = mx & 0xffff, x2m1 = mx >> 16;
            const float* Pp = P + (lo - y0) * PSTR;
            if (x1 > 0) {
                for (int r = lo; r < hi; ++r, Pp += PSTR) acc += Pp[x2m1] - Pp[x1 - 1];
            } else {
                for (int r = lo; r < hi; ++r, Pp += PSTR) acc += Pp[x2m1];
            }
        }
        outp[j] = acc;
    }
}

// ---------------------------------------------------------------------------
// K2: 32 blocks. Blocks 0..15: det finalize for batch b (coalesced row-major
// band accumulation, fixed order). Blocks 16..31: plate IoU + OCR for b-16.
// ---------------------------------------------------------------------------
__global__ __launch_bounds__(256) void k_small(const float* __restrict__ det_boxes,
                                               const float* __restrict__ confV,
                                               const float* __restrict__ plate_boxes,
                                               const float* __restrict__ plate_conf,
                                               const float* __restrict__ ocr,
                                               const float* __restrict__ detPartial,
                                               const int* __restrict__ metaX,
                                               const int* __restrict__ metaY,
                                               float* __restrict__ detBatch,
                                               float* __restrict__ platePart,
                                               float* __restrict__ plateCnt,
                                               float* __restrict__ ocrPart) {
    const int t = threadIdx.x;
    if (blockIdx.x < BB) {
        const int b = blockIdx.x;
        // coalesced accumulation over bands: thread t owns boxes t, t+256
        const float* dp = detPartial + (size_t)b * NBAND * NN;
        float s0 = 0.f, s1 = 0.f;
        const int j1 = t + 256;
        for (int g = 0; g < NBAND; ++g) {
            const float* row = dp + (size_t)g * NN;
            if (t < NN)  s0 += row[t];
            if (j1 < NN) s1 += row[j1];
        }
        float contrib = 0.f;
        if (t < NN) {
            int my = metaY[b * NN + t];
            if (my) {
                int mx = metaX[b * NN + t];
                int x1 = mx & 0xffff, x2 = (mx >> 16) + 1;
                int y1 = my & 0xffff, y2 = my >> 16;
                float area = (float)((y2 - y1) * (x2 - x1));
                contrib = relu_f(s0 / area) * confV[b * NN + t];
            }
        }
        if (j1 < NN) {
            int my = metaY[b * NN + j1];
            if (my) {
                int mx = metaX[b * NN + j1];
                int x1 = mx & 0xffff, x2 = (mx >> 16) + 1;
                int y1 = my & 0xffff, y2 = my >> 16;
                float area = (float)((y2 - y1) * (x2 - x1));
                contrib += relu_f(s1 / area) * confV[b * NN + j1];
            }
        }
        __shared__ float red[256];
        red[t] = contrib;
        __syncthreads();
        for (int k = 128; k > 0; k >>= 1) {
            if (t < k) red[t] += red[t + k];
            __syncthreads();
        }
        if (t == 0) detBatch[b] = red[0];
    } else {
        const float CONF_TH = 0.3f, MIN_IOU = 0.5f, OCR_TH = 0.7f;
        const int b = blockIdx.x - BB;

        __shared__ float vx1[NN], vy1[NN], vx2[NN], vy2[NN], va[NN], vcf[NN];
        __shared__ int anyv;
        __shared__ float redf[256];
        __shared__ int   redi[256];

        if (t == 0) anyv = 0;
        __syncthreads();

        for (int j = t; j < NN; j += 256) {
            const float* bxp = det_boxes + ((size_t)b * NN + j) * 4;
            float cx = bxp[0], cy = bxp[1], w = bxp[2], h = bxp[3];
            float x1 = cx - w * 0.5f, y1 = cy - h * 0.5f;
            float x2 = cx + w * 0.5f, y2 = cy + h * 0.5f;
            vx1[j] = x1; vy1[j] = y1; vx2[j] = x2; vy2[j] = y2;
            va[j] = (x2 - x1) * (y2 - y1);
            float cc = confV[b * NN + j];
            vcf[j] = cc;
            if (cc > CONF_TH) atomicOr(&anyv, 1);
        }
        __syncthreads();

        float term = 0.f; int pv = 0; float pcf = -1e30f;
        if (t < PP) {
            const float* bxp = plate_boxes + ((size_t)b * PP + t) * 4;
            float cx = bxp[0], cy = bxp[1], w = bxp[2], h = bxp[3];
            float px1 = cx - w * 0.5f, py1 = cy - h * 0.5f;
            float px2 = cx + w * 0.5f, py2 = cy + h * 0.5f;
            float a1 = (px2 - px1) * (py2 - py1);
            pcf = plate_conf[b * PP + t];
            pv = (pcf > CONF_TH) ? 1 : 0;
            float max_iou = -1.f;
            for (int j = 0; j < NN; ++j) {
                if (vcf[j] > CONF_TH) {
                    float ltx = fmaxf(px1, vx1[j]);
                    float lty = fmaxf(py1, vy1[j]);
                    float rbx = fminf(px2, vx2[j]);
                    float rby = fminf(py2, vy2[j]);
                    float iw = fmaxf(rbx - ltx, 0.f);
                    float ih = fmaxf(rby - lty, 0.f);
                    float inter = iw * ih;
                    float uni = a1 + va[j] - inter;
                    float iou = inter / (uni + 1e-8f);
                    max_iou = fmaxf(max_iou, iou);
                }
            }
            if (pv) term = relu_f(MIN_IOU - max_iou) * pcf;
        }

        redf[t] = term; redi[t] = pv;
        __syncthreads();
        for (int k = 128; k > 0; k >>= 1) {
            if (t < k) { redf[t] += redf[t + k]; redi[t] += redi[t + k]; }
            __syncthreads();
        }
        float termsum = redf[0];
        int   cnt     = redi[0];
        __syncthreads();

        float osum = 0.f;
        if (t < LL) {
            const float* op = ocr + ((size_t)b * LL + t) * 37;
            float m = op[0];
            #pragma unroll
            for (int i = 1; i < 37; ++i) m = fmaxf(m, op[i]);
            osum = m;
        }
        redf[t] = osum;
        __syncthreads();
        for (int k = 128; k > 0; k >>= 1) {
            if (t < k) redf[t] += redf[t + k];
            __syncthreads();
        }
        float avg_ocr = redf[0] / (float)LL;
        __syncthreads();

        redf[t] = (t < PP) ? pcf : -1e30f;
        __syncthreads();
        for (int k = 128; k > 0; k >>= 1) {
            if (t < k) redf[t] = fmaxf(redf[t], redf[t + k]);
            __syncthreads();
        }
        float max_plate = redf[0];

        if (t == 0) {
            platePart[b] = (cnt > 0 && anyv) ? termsum : 0.f;
            plateCnt[b]  = (float)cnt;
            ocrPart[b]   = (avg_ocr > OCR_TH) ? relu_f(avg_ocr - max_plate) : 0.f;
        }
    }
}

// ---------------------------------------------------------------------------
// K3: final deterministic combine (fixed order, f64).
// ---------------------------------------------------------------------------
__global__ __launch_bounds__(64) void k_final(const float* __restrict__ detBatch,
                                              const float* __restrict__ platePart,
                                              const float* __restrict__ plateCnt,
                                              const float* __restrict__ ocrPart,
                                              float* __restrict__ out) {
    if (threadIdx.x == 0 && blockIdx.x == 0) {
        double ds = 0.0, ps = 0.0, pc = 0.0, os = 0.0;
        for (int b = 0; b < BB; ++b) {
            ds += (double)detBatch[b];
            ps += (double)platePart[b];
            pc += (double)plateCnt[b];
            os += (double)ocrPart[b];
        }
        float det_seg   = (float)ds / (float)(BB * NN);
        float plate_det = (float)ps / fmaxf((float)pc, 1.f);
        float ocr_plate = (float)os / (float)BB;
        out[0] = 0.1f * det_seg + 0.1f * plate_det + 0.1f * ocr_plate;
    }
}

extern "C" void kernel_launch(void* const* d_in, const int* in_sizes, int n_in,
                              void* d_out, int out_size, void* d_ws, size_t ws_size,
                              hipStream_t stream) {
    const float* det_boxes   = (const float*)d_in[0];
    const float* det_logits  = (const float*)d_in[1];
    const float* seg_masks   = (const float*)d_in[2];
    const float* plate_boxes = (const float*)d_in[3];
    const float* plate_conf  = (const float*)d_in[4];
    const float* ocr_probs   = (const float*)d_in[5];
    float* out = (float*)d_out;

    // workspace layout
    float* detPartial = (float*)d_ws;                          // BB*NBAND*NN
    float* detBatch   = detPartial + (size_t)BB * NBAND * NN;  // 16
    float* platePart  = detBatch + BB;                         // 16
    float* plateCnt   = platePart + BB;                        // 16
    float* ocrPart    = plateCnt + BB;                         // 16
    float* confV      = ocrPart + BB;                          // 4800
    int*   metaX      = (int*)(confV + BB * NN);               // 4800
    int*   metaY      = metaX + BB * NN;                       // 4800

    k_meta<<<NDETBLK, 256, 0, stream>>>(det_boxes, det_logits, metaX, metaY, confV);
    k_band<<<BB * NBAND, 256, 0, stream>>>(seg_masks, metaX, metaY, detPartial);
    k_small<<<2 * BB, 256, 0, stream>>>(det_boxes, confV, plate_boxes,
                                        plate_conf, ocr_probs, detPartial,
                                        metaX, metaY,
                                        detBatch, platePart, plateCnt, ocrPart);
    k_final<<<1, 64, 0, stream>>>(detBatch, platePart, plateCnt, ocrPart, out);
}

// Round 10
// 67.413 us; speedup vs baseline: 1.5159x; 1.1067x over previous
//
#include <hip/hip_runtime.h>

#define BB 16
#define NN 300
#define PP 100
#define LL 32
#define HH 768
#define WW 768
#define BAND 16                 // rows per band-block
#define NBAND (HH / BAND)       // 48
#define PSTR 772                // LDS row stride in floats (16B-aligned)
#define NDETBLK 19              // ceil(4800/256)

__device__ __forceinline__ float relu_f(float x) { return fmaxf(x, 0.f); }

// ---------------------------------------------------------------------------
// K1: one block per (batch, 16-row band). Phase A: row prefixes into LDS with
// NO cross-lane ops: lane-local 12-float prefix (registers) -> fine write ->
// broadcast-read of lane totals (P[12i+11], same-wave lockstep, conflict-free)
// -> predicated exclusive accumulate -> rewrite with offset.
// Phase B: thread-per-box LDS lookups. Grid 768 x 512; LDS 51.8KB -> 3/CU.
// ---------------------------------------------------------------------------
__global__ __launch_bounds__(512) void k_band(const float* __restrict__ seg,
                                              const float* __restrict__ det_boxes,
                                              const float* __restrict__ logits,
                                              float* __restrict__ detPartial) {
    const int blk  = blockIdx.x;
    const int b    = blk / NBAND;
    const int band = blk % NBAND;
    const int y0   = band * BAND;
    const int t    = threadIdx.x;
    const int wave = t >> 6, lane = t & 63;

    __shared__ float P[BAND * PSTR];   // 49408 B
    __shared__ int metaX[NN];          // x1 | ((x2-1) << 16), 0 if invalid
    __shared__ int metaY[NN];          // y1 | (y2 << 16),     0 if invalid

    // ---- Phase 0: box metadata (each thread <=1 box) -----------------------
    for (int j = t; j < NN; j += 512) {
        const float* lg = logits + ((size_t)b * NN + j) * 7;
        float m = lg[0];
        #pragma unroll
        for (int i = 1; i < 7; ++i) m = fmaxf(m, lg[i]);
        float sum = 0.f;
        #pragma unroll
        for (int i = 0; i < 7; ++i) sum += expf(lg[i] - m);
        float conf = 1.f / sum;

        const float* bxp = det_boxes + ((size_t)b * NN + j) * 4;
        float cx = bxp[0], cy = bxp[1], w = bxp[2], h = bxp[3];
        int x1 = (int)floorf((cx - w * 0.5f) * (float)WW);
        int y1 = (int)floorf((cy - h * 0.5f) * (float)HH);
        int x2 = (int)floorf((cx + w * 0.5f) * (float)WW);
        int y2 = (int)floorf((cy + h * 0.5f) * (float)HH);
        x1 = min(max(x1, 0), WW - 1); y1 = min(max(y1, 0), HH - 1);
        x2 = min(max(x2, 0), WW - 1); y2 = min(max(y2, 0), HH - 1);
        bool valid = (conf >= 0.3f) && (x2 > x1) && (y2 > y1);
        metaX[j] = valid ? (x1 | ((x2 - 1) << 16)) : 0;
        metaY[j] = valid ? (y1 | (y2 << 16)) : 0;
    }

    // ---- Phase A: 8 waves x 2 rows, zero cross-lane ops --------------------
    #pragma unroll
    for (int rr = 0; rr < 2; ++rr) {
        const int r = wave * 2 + rr;
        const int y = y0 + r;
        const float* p1 = seg + ((size_t)(b * 3 + 1) * HH + y) * WW + 12 * lane;
        const float* p2 = seg + ((size_t)(b * 3 + 2) * HH + y) * WW + 12 * lane;
        float4 A0 = *(const float4*)(p1);
        float4 A1 = *(const float4*)(p1 + 4);
        float4 A2 = *(const float4*)(p1 + 8);
        float4 B0 = *(const float4*)(p2);
        float4 B1 = *(const float4*)(p2 + 4);
        float4 B2 = *(const float4*)(p2 + 8);
        // lane-local inclusive prefix over 12 diffs (registers, static)
        float f0  = B0.x - A0.x;
        float f1  = f0 + (B0.y - A0.y);
        float f2  = f1 + (B0.z - A0.z);
        float f3  = f2 + (B0.w - A0.w);
        float f4  = f3 + (B1.x - A1.x);
        float f5  = f4 + (B1.y - A1.y);
        float f6  = f5 + (B1.z - A1.z);
        float f7  = f6 + (B1.w - A1.w);
        float f8  = f7 + (B2.x - A2.x);
        float f9  = f8 + (B2.y - A2.y);
        float f10 = f9 + (B2.z - A2.z);
        float f11 = f10 + (B2.w - A2.w);

        float* Prow = P + r * PSTR;
        float* Pl   = Prow + 12 * lane;
        // write fine-only prefix (totals land at Prow[12*lane+11])
        float4 w0 = { f0, f1, f2,  f3  };
        float4 w1 = { f4, f5, f6,  f7  };
        float4 w2 = { f8, f9, f10, f11 };
        *(float4*)(Pl)     = w0;
        *(float4*)(Pl + 4) = w1;
        *(float4*)(Pl + 8) = w2;

        // broadcast-read lane totals of THIS wave's row; predicated exclusive
        // accumulate. Same-wave lockstep: all reads complete before rewrites.
        float e = 0.f;
        for (int i = 0; i < 63; ++i) {
            float tv = Prow[12 * i + 11];
            if (i < lane) e += tv;
        }
        // rewrite with exclusive offset added
        float4 u0 = { f0 + e, f1 + e, f2  + e, f3  + e };
        float4 u1 = { f4 + e, f5 + e, f6  + e, f7  + e };
        float4 u2 = { f8 + e, f9 + e, f10 + e, f11 + e };
        *(float4*)(Pl)     = u0;
        *(float4*)(Pl + 4) = u1;
        *(float4*)(Pl + 8) = u2;
    }
    __syncthreads();

    // ---- Phase B+C: per-box accumulation over band rows, contiguous write --
    float* outp = detPartial + ((size_t)b * NBAND + band) * NN;
    for (int j = t; j < NN; j += 512) {
        int mx = metaX[j], my = metaY[j];
        int y1 = my & 0xffff, y2 = my >> 16;
        int lo = max(y1, y0), hi = min(y2, y0 + BAND);
        float acc = 0.f;
        if (lo < hi) {
            int x1 = mx & 0xffff, x2m1 = mx >> 16;
            const float* Pp = P + (lo - y0) * PSTR;
            if (x1 > 0) {
                for (int r = lo; r < hi; ++r, Pp += PSTR) acc += Pp[x2m1] - Pp[x1 - 1];
            } else {
                for (int r = lo; r < hi; ++r, Pp += PSTR) acc += Pp[x2m1];
            }
        }
        outp[j] = acc;
    }
}

// ---------------------------------------------------------------------------
// K2: blocks 0..18 finalize det term (sum 48 band partials, fixed order);
//     blocks 19..34 do plate IoU + OCR for batch b = blk-19.
// ---------------------------------------------------------------------------
__global__ __launch_bounds__(256) void k_small(const float* __restrict__ det_boxes,
                                               const float* __restrict__ logits,
                                               const float* __restrict__ plate_boxes,
                                               const float* __restrict__ plate_conf,
                                               const float* __restrict__ ocr,
                                               const float* __restrict__ detPartial,
                                               float* __restrict__ detPart,
                                               float* __restrict__ platePart,
                                               float* __restrict__ plateCnt,
                                               float* __restrict__ ocrPart) {
    const int t = threadIdx.x;
    if (blockIdx.x < NDETBLK) {
        const int idx = blockIdx.x * 256 + t;
        float contrib = 0.f;
        if (idx < BB * NN) {
            const int b = idx / NN, j = idx % NN;
            const float* lg = logits + (size_t)idx * 7;
            float m = lg[0];
            #pragma unroll
            for (int i = 1; i < 7; ++i) m = fmaxf(m, lg[i]);
            float ssum = 0.f;
            #pragma unroll
            for (int i = 0; i < 7; ++i) ssum += expf(lg[i] - m);
            float conf = 1.f / ssum;

            const float* bxp = det_boxes + (size_t)idx * 4;
            float cx = bxp[0], cy = bxp[1], w = bxp[2], h = bxp[3];
            int x1 = (int)floorf((cx - w * 0.5f) * (float)WW);
            int y1 = (int)floorf((cy - h * 0.5f) * (float)HH);
            int x2 = (int)floorf((cx + w * 0.5f) * (float)WW);
            int y2 = (int)floorf((cy + h * 0.5f) * (float)HH);
            x1 = min(max(x1, 0), WW - 1); y1 = min(max(y1, 0), HH - 1);
            x2 = min(max(x2, 0), WW - 1); y2 = min(max(y2, 0), HH - 1);
            if (conf >= 0.3f && x2 > x1 && y2 > y1) {
                const float* pp = detPartial + (size_t)b * NBAND * NN + j;
                float s0 = 0.f, s1 = 0.f;
                for (int g2 = 0; g2 < NBAND; g2 += 2) {
                    s0 += pp[(size_t)g2 * NN];
                    s1 += pp[(size_t)(g2 + 1) * NN];
                }
                float Sb = s0 + s1;
                float area = (float)((y2 - y1) * (x2 - x1));
                contrib = relu_f(Sb / area) * conf;
            }
        }
        __shared__ float red[256];
        red[t] = contrib;
        __syncthreads();
        for (int k = 128; k > 0; k >>= 1) {
            if (t < k) red[t] += red[t + k];
            __syncthreads();
        }
        if (t == 0) detPart[blockIdx.x] = red[0];
    } else {
        const float CONF_TH = 0.3f, MIN_IOU = 0.5f, OCR_TH = 0.7f;
        const int b = blockIdx.x - NDETBLK;

        __shared__ float vx1[NN], vy1[NN], vx2[NN], vy2[NN], va[NN], vcf[NN];
        __shared__ int anyv;
        __shared__ float redf[256];
        __shared__ int   redi[256];

        if (t == 0) anyv = 0;
        __syncthreads();

        for (int j = t; j < NN; j += 256) {
            const float* bxp = det_boxes + ((size_t)b * NN + j) * 4;
            float cx = bxp[0], cy = bxp[1], w = bxp[2], h = bxp[3];
            float x1 = cx - w * 0.5f, y1 = cy - h * 0.5f;
            float x2 = cx + w * 0.5f, y2 = cy + h * 0.5f;
            vx1[j] = x1; vy1[j] = y1; vx2[j] = x2; vy2[j] = y2;
            va[j] = (x2 - x1) * (y2 - y1);
            const float* lg = logits + ((size_t)b * NN + j) * 7;
            float m = lg[0];
            #pragma unroll
            for (int i = 1; i < 7; ++i) m = fmaxf(m, lg[i]);
            float sum = 0.f;
            #pragma unroll
            for (int i = 0; i < 7; ++i) sum += expf(lg[i] - m);
            float cc = 1.f / sum;
            vcf[j] = cc;
            if (cc > CONF_TH) atomicOr(&anyv, 1);
        }
        __syncthreads();

        float term = 0.f; int pv = 0; float pcf = -1e30f;
        if (t < PP) {
            const float* bxp = plate_boxes + ((size_t)b * PP + t) * 4;
            float cx = bxp[0], cy = bxp[1], w = bxp[2], h = bxp[3];
            float px1 = cx - w * 0.5f, py1 = cy - h * 0.5f;
            float px2 = cx + w * 0.5f, py2 = cy + h * 0.5f;
            float a1 = (px2 - px1) * (py2 - py1);
            pcf = plate_conf[b * PP + t];
            pv = (pcf > CONF_TH) ? 1 : 0;
            float max_iou = -1.f;
            for (int j = 0; j < NN; ++j) {
                if (vcf[j] > CONF_TH) {
                    float ltx = fmaxf(px1, vx1[j]);
                    float lty = fmaxf(py1, vy1[j]);
                    float rbx = fminf(px2, vx2[j]);
                    float rby = fminf(py2, vy2[j]);
                    float iw = fmaxf(rbx - ltx, 0.f);
                    float ih = fmaxf(rby - lty, 0.f);
                    float inter = iw * ih;
                    float uni = a1 + va[j] - inter;
                    float iou = inter / (uni + 1e-8f);
                    max_iou = fmaxf(max_iou, iou);
                }
            }
            if (pv) term = relu_f(MIN_IOU - max_iou) * pcf;
        }

        redf[t] = term; redi[t] = pv;
        __syncthreads();
        for (int k = 128; k > 0; k >>= 1) {
            if (t < k) { redf[t] += redf[t + k]; redi[t] += redi[t + k]; }
            __syncthreads();
        }
        float termsum = redf[0];
        int   cnt     = redi[0];
        __syncthreads();

        float osum = 0.f;
        if (t < LL) {
            const float* op = ocr + ((size_t)b * LL + t) * 37;
            float m = op[0];
            #pragma unroll
            for (int i = 1; i < 37; ++i) m = fmaxf(m, op[i]);
            osum = m;
        }
        redf[t] = osum;
        __syncthreads();
        for (int k = 128; k > 0; k >>= 1) {
            if (t < k) redf[t] += redf[t + k];
            __syncthreads();
        }
        float avg_ocr = redf[0] / (float)LL;
        __syncthreads();

        redf[t] = (t < PP) ? pcf : -1e30f;
        __syncthreads();
        for (int k = 128; k > 0; k >>= 1) {
            if (t < k) redf[t] = fmaxf(redf[t], redf[t + k]);
            __syncthreads();
        }
        float max_plate = redf[0];

        if (t == 0) {
            platePart[b] = (cnt > 0 && anyv) ? termsum : 0.f;
            plateCnt[b]  = (float)cnt;
            ocrPart[b]   = (avg_ocr > OCR_TH) ? relu_f(avg_ocr - max_plate) : 0.f;
        }
    }
}

// ---------------------------------------------------------------------------
// K3: final deterministic combine.
// ---------------------------------------------------------------------------
__global__ __launch_bounds__(64) void k_final(const float* __restrict__ detPart,
                                              const float* __restrict__ platePart,
                                              const float* __restrict__ plateCnt,
                                              const float* __restrict__ ocrPart,
                                              float* __restrict__ out) {
    if (threadIdx.x == 0 && blockIdx.x == 0) {
        double ds = 0.0;
        for (int i = 0; i < NDETBLK; ++i) ds += (double)detPart[i];
        double ps = 0.0, cnt = 0.0, os = 0.0;
        for (int b = 0; b < BB; ++b) {
            ps  += (double)platePart[b];
            cnt += (double)plateCnt[b];
            os  += (double)ocrPart[b];
        }
        float det_seg   = (float)ds / (float)(BB * NN);
        float plate_det = (float)ps / fmaxf((float)cnt, 1.f);
        float ocr_plate = (float)os / (float)BB;
        out[0] = 0.1f * det_seg + 0.1f * plate_det + 0.1f * ocr_plate;
    }
}

extern "C" void kernel_launch(void* const* d_in, const int* in_sizes, int n_in,
                              void* d_out, int out_size, void* d_ws, size_t ws_size,
                              hipStream_t stream) {
    const float* det_boxes   = (const float*)d_in[0];
    const float* det_logits  = (const float*)d_in[1];
    const float* seg_masks   = (const float*)d_in[2];
    const float* plate_boxes = (const float*)d_in[3];
    const float* plate_conf  = (const float*)d_in[4];
    const float* ocr_probs   = (const float*)d_in[5];
    float* out = (float*)d_out;

    // workspace layout (floats)
    float* detPartial = (float*)d_ws;                          // B*NBAND*N = 230400
    float* detPart    = detPartial + (size_t)BB * NBAND * NN;  // 19
    float* platePart  = detPart + NDETBLK;                     // 16
    float* plateCnt   = platePart + BB;                        // 16
    float* ocrPart    = plateCnt + BB;                         // 16

    k_band<<<BB * NBAND, 512, 0, stream>>>(seg_masks, det_boxes, det_logits,
                                           detPartial);
    k_small<<<NDETBLK + BB, 256, 0, stream>>>(det_boxes, det_logits, plate_boxes,
                                              plate_conf, ocr_probs, detPartial,
                                              detPart, platePart, plateCnt, ocrPart);
    k_final<<<1, 64, 0, stream>>>(detPart, platePart, plateCnt, ocrPart, out);
}

// Round 12
// 63.088 us; speedup vs baseline: 1.6198x; 1.0685x over previous
//
#include <hip/hip_runtime.h>

#define BB 16
#define NN 300
#define PP 100
#define LL 32
#define HH 768
#define WW 768
#define BAND 16                 // rows per band-block
#define NBAND (HH / BAND)       // 48
#define PSTR 772                // LDS row stride in floats (16B-aligned)
#define NDETBLK 19              // ceil(4800/256)

__device__ __forceinline__ float relu_f(float x) { return fmaxf(x, 0.f); }

// ---------------------------------------------------------------------------
// K1: one block per (batch, 16-row band). Phase A: row prefix sums of
// d = seg[2]-seg[1] into LDS via float4 streaming loads + wave shuffle scan.
// Phase B: one thread per box accumulates P[r][x2-1]-P[r][x1-1] over the
// band's rows. Phase C: contiguous 300-float partial write. No atomics.
// Grid: 768 blocks of 512 threads; LDS 51.8 KB -> 3 blocks/CU, 24 waves/CU.
// (R5 structure — best measured: 62.8 us total, absmax 0.0.)
// ---------------------------------------------------------------------------
__global__ __launch_bounds__(512) void k_band(const float* __restrict__ seg,
                                              const float* __restrict__ det_boxes,
                                              const float* __restrict__ logits,
                                              float* __restrict__ detPartial) {
    const int blk  = blockIdx.x;
    const int b    = blk / NBAND;
    const int band = blk % NBAND;
    const int y0   = band * BAND;
    const int t    = threadIdx.x;
    const int wave = t >> 6, lane = t & 63;

    __shared__ float P[BAND * PSTR];   // 49408 B
    __shared__ int metaX[NN];          // x1 | ((x2-1) << 16), 0 if invalid
    __shared__ int metaY[NN];          // y1 | (y2 << 16),     0 if invalid

    // ---- Phase 0: box metadata (each thread <=1 box) -----------------------
    for (int j = t; j < NN; j += 512) {
        const float* lg = logits + ((size_t)b * NN + j) * 7;
        float m = lg[0];
        #pragma unroll
        for (int i = 1; i < 7; ++i) m = fmaxf(m, lg[i]);
        float sum = 0.f;
        #pragma unroll
        for (int i = 0; i < 7; ++i) sum += expf(lg[i] - m);
        float conf = 1.f / sum;

        const float* bxp = det_boxes + ((size_t)b * NN + j) * 4;
        float cx = bxp[0], cy = bxp[1], w = bxp[2], h = bxp[3];
        int x1 = (int)floorf((cx - w * 0.5f) * (float)WW);
        int y1 = (int)floorf((cy - h * 0.5f) * (float)HH);
        int x2 = (int)floorf((cx + w * 0.5f) * (float)WW);
        int y2 = (int)floorf((cy + h * 0.5f) * (float)HH);
        x1 = min(max(x1, 0), WW - 1); y1 = min(max(y1, 0), HH - 1);
        x2 = min(max(x2, 0), WW - 1); y2 = min(max(y2, 0), HH - 1);
        bool valid = (conf >= 0.3f) && (x2 > x1) && (y2 > y1);
        metaX[j] = valid ? (x1 | ((x2 - 1) << 16)) : 0;
        metaY[j] = valid ? (y1 | (y2 << 16)) : 0;   // empty y-range if invalid
    }

    // ---- Phase A: 8 waves x 2 rows, float4 stream + shuffle scan -----------
    const float4* r1base = (const float4*)(seg + (size_t)(b * 3 + 1) * HH * WW);
    const float4* r2base = (const float4*)(seg + (size_t)(b * 3 + 2) * HH * WW);
    #pragma unroll
    for (int rr = 0; rr < 2; ++rr) {
        const int r = wave * 2 + rr;
        const int y = y0 + r;
        const float4* q1 = r1base + (size_t)y * (WW / 4);
        const float4* q2 = r2base + (size_t)y * (WW / 4);
        float* Prow = P + r * PSTR;
        float carry = 0.f;
        #pragma unroll
        for (int c = 0; c < 3; ++c) {
            float4 a = q1[c * 64 + lane];
            float4 o = q2[c * 64 + lane];
            float dx = o.x - a.x, dy = o.y - a.y, dz = o.z - a.z, dw = o.w - a.w;
            float s = dx + dy + dz + dw;
            float incl = s;
            #pragma unroll
            for (int d = 1; d < 64; d <<= 1) {
                float u = __shfl_up(incl, d, 64);
                if (lane >= d) incl += u;
            }
            float base = carry + incl - s;
            float4 pv;
            pv.x = base + dx; pv.y = pv.x + dy; pv.z = pv.y + dz; pv.w = pv.z + dw;
            *(float4*)(Prow + c * 256 + lane * 4) = pv;
            carry += __shfl(incl, 63, 64);
        }
    }
    __syncthreads();

    // ---- Phase B+C: per-box accumulation over band rows, contiguous write --
    float* outp = detPartial + ((size_t)b * NBAND + band) * NN;
    for (int j = t; j < NN; j += 512) {
        int mx = metaX[j], my = metaY[j];
        int y1 = my & 0xffff, y2 = my >> 16;
        int lo = max(y1, y0), hi = min(y2, y0 + BAND);
        float acc = 0.f;
        if (lo < hi) {
            int x1 = mx & 0xffff, x2m1 = mx >> 16;
            const float* Pp = P + (lo - y0) * PSTR;
            if (x1 > 0) {
                for (int r = lo; r < hi; ++r, Pp += PSTR) acc += Pp[x2m1] - Pp[x1 - 1];
            } else {
                for (int r = lo; r < hi; ++r, Pp += PSTR) acc += Pp[x2m1];
            }
        }
        outp[j] = acc;
    }
}

// ---------------------------------------------------------------------------
// K2: blocks 0..18 finalize det term (sum 48 band partials, fixed order);
//     blocks 19..34 do plate IoU + OCR for batch b = blk-19.
// ---------------------------------------------------------------------------
__global__ __launch_bounds__(256) void k_small(const float* __restrict__ det_boxes,
                                               const float* __restrict__ logits,
                                               const float* __restrict__ plate_boxes,
                                               const float* __restrict__ plate_conf,
                                               const float* __restrict__ ocr,
                                               const float* __restrict__ detPartial,
                                               float* __restrict__ detPart,
                                               float* __restrict__ platePart,
                                               float* __restrict__ plateCnt,
                                               float* __restrict__ ocrPart) {
    const int t = threadIdx.x;
    if (blockIdx.x < NDETBLK) {
        const int idx = blockIdx.x * 256 + t;
        float contrib = 0.f;
        if (idx < BB * NN) {
            const int b = idx / NN, j = idx % NN;
            const float* lg = logits + (size_t)idx * 7;
            float m = lg[0];
            #pragma unroll
            for (int i = 1; i < 7; ++i) m = fmaxf(m, lg[i]);
            float ssum = 0.f;
            #pragma unroll
            for (int i = 0; i < 7; ++i) ssum += expf(lg[i] - m);
            float conf = 1.f / ssum;

            const float* bxp = det_boxes + (size_t)idx * 4;
            float cx = bxp[0], cy = bxp[1], w = bxp[2], h = bxp[3];
            int x1 = (int)floorf((cx - w * 0.5f) * (float)WW);
            int y1 = (int)floorf((cy - h * 0.5f) * (float)HH);
            int x2 = (int)floorf((cx + w * 0.5f) * (float)WW);
            int y2 = (int)floorf((cy + h * 0.5f) * (float)HH);
            x1 = min(max(x1, 0), WW - 1); y1 = min(max(y1, 0), HH - 1);
            x2 = min(max(x2, 0), WW - 1); y2 = min(max(y2, 0), HH - 1);
            if (conf >= 0.3f && x2 > x1 && y2 > y1) {
                const float* pp = detPartial + (size_t)b * NBAND * NN + j;
                float Sb = 0.f;
                #pragma unroll
                for (int g2 = 0; g2 < NBAND; ++g2) Sb += pp[(size_t)g2 * NN];
                float area = (float)((y2 - y1) * (x2 - x1));
                contrib = relu_f(Sb / area) * conf;
            }
        }
        __shared__ float red[256];
        red[t] = contrib;
        __syncthreads();
        for (int k = 128; k > 0; k >>= 1) {
            if (t < k) red[t] += red[t + k];
            __syncthreads();
        }
        if (t == 0) detPart[blockIdx.x] = red[0];
    } else {
        const float CONF_TH = 0.3f, MIN_IOU = 0.5f, OCR_TH = 0.7f;
        const int b = blockIdx.x - NDETBLK;

        __shared__ float vx1[NN], vy1[NN], vx2[NN], vy2[NN], va[NN], vcf[NN];
        __shared__ int anyv;
        __shared__ float redf[256];
        __shared__ int   redi[256];

        if (t == 0) anyv = 0;
        __syncthreads();

        for (int j = t; j < NN; j += 256) {
            const float* bxp = det_boxes + ((size_t)b * NN + j) * 4;
            float cx = bxp[0], cy = bxp[1], w = bxp[2], h = bxp[3];
            float x1 = cx - w * 0.5f, y1 = cy - h * 0.5f;
            float x2 = cx + w * 0.5f, y2 = cy + h * 0.5f;
            vx1[j] = x1; vy1[j] = y1; vx2[j] = x2; vy2[j] = y2;
            va[j] = (x2 - x1) * (y2 - y1);
            const float* lg = logits + ((size_t)b * NN + j) * 7;
            float m = lg[0];
            #pragma unroll
            for (int i = 1; i < 7; ++i) m = fmaxf(m, lg[i]);
            float sum = 0.f;
            #pragma unroll
            for (int i = 0; i < 7; ++i) sum += expf(lg[i] - m);
            float cc = 1.f / sum;
            vcf[j] = cc;
            if (cc > CONF_TH) atomicOr(&anyv, 1);
        }
        __syncthreads();

        float term = 0.f; int pv = 0; float pcf = -1e30f;
        if (t < PP) {
            const float* bxp = plate_boxes + ((size_t)b * PP + t) * 4;
            float cx = bxp[0], cy = bxp[1], w = bxp[2], h = bxp[3];
            float px1 = cx - w * 0.5f, py1 = cy - h * 0.5f;
            float px2 = cx + w * 0.5f, py2 = cy + h * 0.5f;
            float a1 = (px2 - px1) * (py2 - py1);
            pcf = plate_conf[b * PP + t];
            pv = (pcf > CONF_TH) ? 1 : 0;
            float max_iou = -1.f;
            for (int j = 0; j < NN; ++j) {
                if (vcf[j] > CONF_TH) {
                    float ltx = fmaxf(px1, vx1[j]);
                    float lty = fmaxf(py1, vy1[j]);
                    float rbx = fminf(px2, vx2[j]);
                    float rby = fminf(py2, vy2[j]);
                    float iw = fmaxf(rbx - ltx, 0.f);
                    float ih = fmaxf(rby - lty, 0.f);
                    float inter = iw * ih;
                    float uni = a1 + va[j] - inter;
                    float iou = inter / (uni + 1e-8f);
                    max_iou = fmaxf(max_iou, iou);
                }
            }
            if (pv) term = relu_f(MIN_IOU - max_iou) * pcf;
        }

        redf[t] = term; redi[t] = pv;
        __syncthreads();
        for (int k = 128; k > 0; k >>= 1) {
            if (t < k) { redf[t] += redf[t + k]; redi[t] += redi[t + k]; }
            __syncthreads();
        }
        float termsum = redf[0];
        int   cnt     = redi[0];
        __syncthreads();

        float osum = 0.f;
        if (t < LL) {
            const float* op = ocr + ((size_t)b * LL + t) * 37;
            float m = op[0];
            #pragma unroll
            for (int i = 1; i < 37; ++i) m = fmaxf(m, op[i]);
            osum = m;
        }
        redf[t] = osum;
        __syncthreads();
        for (int k = 128; k > 0; k >>= 1) {
            if (t < k) redf[t] += redf[t + k];
            __syncthreads();
        }
        float avg_ocr = redf[0] / (float)LL;
        __syncthreads();

        redf[t] = (t < PP) ? pcf : -1e30f;
        __syncthreads();
        for (int k = 128; k > 0; k >>= 1) {
            if (t < k) redf[t] = fmaxf(redf[t], redf[t + k]);
            __syncthreads();
        }
        float max_plate = redf[0];

        if (t == 0) {
            platePart[b] = (cnt > 0 && anyv) ? termsum : 0.f;
            plateCnt[b]  = (float)cnt;
            ocrPart[b]   = (avg_ocr > OCR_TH) ? relu_f(avg_ocr - max_plate) : 0.f;
        }
    }
}

// ---------------------------------------------------------------------------
// K3: final deterministic combine.
// ---------------------------------------------------------------------------
__global__ __launch_bounds__(64) void k_final(const float* __restrict__ detPart,
                                              const float* __restrict__ platePart,
                                              const float* __restrict__ plateCnt,
                                              const float* __restrict__ ocrPart,
                                              float* __restrict__ out) {
    if (threadIdx.x == 0 && blockIdx.x == 0) {
        double ds = 0.0;
        for (int i = 0; i < NDETBLK; ++i) ds += (double)detPart[i];
        double ps = 0.0, cnt = 0.0, os = 0.0;
        for (int b = 0; b < BB; ++b) {
            ps  += (double)platePart[b];
            cnt += (double)plateCnt[b];
            os  += (double)ocrPart[b];
        }
        float det_seg   = (float)ds / (float)(BB * NN);
        float plate_det = (float)ps / fmaxf((float)cnt, 1.f);
        float ocr_plate = (float)os / (float)BB;
        out[0] = 0.1f * det_seg + 0.1f * plate_det + 0.1f * ocr_plate;
    }
}

extern "C" void kernel_launch(void* const* d_in, const int* in_sizes, int n_in,
                              void* d_out, int out_size, void* d_ws, size_t ws_size,
                              hipStream_t stream) {
    const float* det_boxes   = (const float*)d_in[0];
    const float* det_logits  = (const float*)d_in[1];
    const float* seg_masks   = (const float*)d_in[2];
    const float* plate_boxes = (const float*)d_in[3];
    const float* plate_conf  = (const float*)d_in[4];
    const float* ocr_probs   = (const float*)d_in[5];
    float* out = (float*)d_out;

    // workspace layout (floats)
    float* detPartial = (float*)d_ws;                          // B*NBAND*N = 230400
    float* detPart    = detPartial + (size_t)BB * NBAND * NN;  // 19
    float* platePart  = detPart + NDETBLK;                     // 16
    float* plateCnt   = platePart + BB;                        // 16
    float* ocrPart    = plateCnt + BB;                         // 16

    k_band<<<BB * NBAND, 512, 0, stream>>>(seg_masks, det_boxes, det_logits,
                                           detPartial);
    k_small<<<NDETBLK + BB, 256, 0, stream>>>(det_boxes, det_logits, plate_boxes,
                                              plate_conf, ocr_probs, detPartial,
                                              detPart, platePart, plateCnt, ocrPart);
    k_final<<<1, 64, 0, stream>>>(detPart, platePart, plateCnt, ocrPart, out);
}